// Round 3
// baseline (211.772 us; speedup 1.0000x reference)
//
#include <hip/hip_runtime.h>

#define BB 64
#define SS 512
#define DD 1024
#define EE 16

// ---------------------------------------------------------------------------
// Kernel 1: ragged gather + sum pool.  4 blocks per b (quarter of D each),
// 64 threads per block; thread t owns float4 #(t) of its 256-float quarter.
// ---------------------------------------------------------------------------
__global__ void pool_kernel(const float* __restrict__ embeds,
                            const int* __restrict__ e1_idx,
                            const int* __restrict__ e2_idx,
                            const int* __restrict__ e1_mask,
                            const int* __restrict__ e2_mask,
                            float* __restrict__ pool1,
                            float* __restrict__ pool2) {
    __shared__ int si1[EE], sm1[EE], si2[EE], sm2[EE];
    int b = blockIdx.x >> 2;
    int q = blockIdx.x & 3;               // quarter of D
    int t = threadIdx.x;                  // 0..63
    if (t < EE) {
        si1[t] = e1_idx[b * EE + t];
        sm1[t] = e1_mask[b * EE + t];
        si2[t] = e2_idx[b * EE + t];
        sm2[t] = e2_mask[b * EE + t];
    }
    __syncthreads();

    int f4 = q * 64 + t;                  // float4 index within D (0..255)
    const float* eb = embeds + (size_t)b * SS * DD;
    float4 s1 = make_float4(0.f, 0.f, 0.f, 0.f);
    float4 s2 = make_float4(0.f, 0.f, 0.f, 0.f);
#pragma unroll
    for (int j = 0; j < EE; ++j) {
        if (sm1[j]) {            // wave-uniform branch
            float4 v = ((const float4*)(eb + (size_t)si1[j] * DD))[f4];
            s1.x += v.x; s1.y += v.y; s1.z += v.z; s1.w += v.w;
        }
        if (sm2[j]) {
            float4 v = ((const float4*)(eb + (size_t)si2[j] * DD))[f4];
            s2.x += v.x; s2.y += v.y; s2.z += v.z; s2.w += v.w;
        }
    }
    ((float4*)(pool1 + (size_t)b * DD))[f4] = s1;
    ((float4*)(pool2 + (size_t)b * DD))[f4] = s2;
}

// ---------------------------------------------------------------------------
// Kernel 2: logits. One wave64 per FOUR rows (b, 4w .. 4w+3).
// Per k-iter each lane loads 4 embed float4s + 2 pool float4s.
// 8 running dots -> shuffle butterfly -> lane0 writes float4 per stream.
// ---------------------------------------------------------------------------
__global__ void dots_kernel(const float* __restrict__ embeds,
                            const float* __restrict__ pool1,
                            const float* __restrict__ pool2,
                            float* __restrict__ l1,
                            float* __restrict__ l2) {
    int gtid = blockIdx.x * blockDim.x + threadIdx.x;
    int wave = gtid >> 6;        // 0 .. B*S/4-1
    int lane = threadIdx.x & 63;
    int s0 = wave * 4;           // first global row id (b*S+s)
    int b = s0 >> 9;             // / SS

    const float4* row0 = (const float4*)(embeds + (size_t)s0 * DD);
    const float4* row1 = (const float4*)(embeds + (size_t)(s0 + 1) * DD);
    const float4* row2 = (const float4*)(embeds + (size_t)(s0 + 2) * DD);
    const float4* row3 = (const float4*)(embeds + (size_t)(s0 + 3) * DD);
    const float4* p1   = (const float4*)(pool1 + (size_t)b * DD);
    const float4* p2   = (const float4*)(pool2 + (size_t)b * DD);

    float a10 = 0.f, a11 = 0.f, a12 = 0.f, a13 = 0.f;
    float a20 = 0.f, a21 = 0.f, a22 = 0.f, a23 = 0.f;
#pragma unroll
    for (int k = 0; k < 4; ++k) {
        int idx = k * 64 + lane;
        float4 q1 = p1[idx];
        float4 q2 = p2[idx];
        float4 e0 = row0[idx];
        float4 e1 = row1[idx];
        float4 e2 = row2[idx];
        float4 e3 = row3[idx];
        a10 += e0.x * q1.x + e0.y * q1.y + e0.z * q1.z + e0.w * q1.w;
        a20 += e0.x * q2.x + e0.y * q2.y + e0.z * q2.z + e0.w * q2.w;
        a11 += e1.x * q1.x + e1.y * q1.y + e1.z * q1.z + e1.w * q1.w;
        a21 += e1.x * q2.x + e1.y * q2.y + e1.z * q2.z + e1.w * q2.w;
        a12 += e2.x * q1.x + e2.y * q1.y + e2.z * q1.z + e2.w * q1.w;
        a22 += e2.x * q2.x + e2.y * q2.y + e2.z * q2.z + e2.w * q2.w;
        a13 += e3.x * q1.x + e3.y * q1.y + e3.z * q1.z + e3.w * q1.w;
        a23 += e3.x * q2.x + e3.y * q2.y + e3.z * q2.z + e3.w * q2.w;
    }
#pragma unroll
    for (int off = 32; off > 0; off >>= 1) {
        a10 += __shfl_down(a10, off, 64);
        a11 += __shfl_down(a11, off, 64);
        a12 += __shfl_down(a12, off, 64);
        a13 += __shfl_down(a13, off, 64);
        a20 += __shfl_down(a20, off, 64);
        a21 += __shfl_down(a21, off, 64);
        a22 += __shfl_down(a22, off, 64);
        a23 += __shfl_down(a23, off, 64);
    }
    if (lane == 0) {
        ((float4*)l1)[wave] = make_float4(a10, a11, a12, a13);
        ((float4*)l2)[wave] = make_float4(a20, a21, a22, a23);
    }
}

// ---------------------------------------------------------------------------
// Kernel 3: softmax over S for both logit sets + average.
// One block (256 threads) per b; each thread owns elements t and t+256.
// ---------------------------------------------------------------------------
__global__ void softmax_kernel(const float* __restrict__ l1,
                               const float* __restrict__ l2,
                               float* __restrict__ out) {
    __shared__ float sm[8];
    int b = blockIdx.x;
    int t = threadIdx.x;
    int wid = t >> 6, lane = t & 63;

    float x1a = l1[b * SS + t],       x2a = l2[b * SS + t];
    float x1b = l1[b * SS + t + 256], x2b = l2[b * SS + t + 256];

    // ---- max reduction, both streams ----
    float v1 = fmaxf(x1a, x1b);
    float v2 = fmaxf(x2a, x2b);
#pragma unroll
    for (int off = 32; off > 0; off >>= 1) {
        v1 = fmaxf(v1, __shfl_down(v1, off, 64));
        v2 = fmaxf(v2, __shfl_down(v2, off, 64));
    }
    if (lane == 0) { sm[wid] = v1; sm[4 + wid] = v2; }
    __syncthreads();
    float m1 = fmaxf(fmaxf(sm[0], sm[1]), fmaxf(sm[2], sm[3]));
    float m2 = fmaxf(fmaxf(sm[4], sm[5]), fmaxf(sm[6], sm[7]));
    __syncthreads();

    float e1a = __expf(x1a - m1), e1b = __expf(x1b - m1);
    float e2a = __expf(x2a - m2), e2b = __expf(x2b - m2);

    // ---- sum reduction, both streams ----
    v1 = e1a + e1b;
    v2 = e2a + e2b;
#pragma unroll
    for (int off = 32; off > 0; off >>= 1) {
        v1 += __shfl_down(v1, off, 64);
        v2 += __shfl_down(v2, off, 64);
    }
    if (lane == 0) { sm[wid] = v1; sm[4 + wid] = v2; }
    __syncthreads();
    float s1 = sm[0] + sm[1] + sm[2] + sm[3];
    float s2 = sm[4] + sm[5] + sm[6] + sm[7];

    float r1 = 1.f / s1, r2 = 1.f / s2;
    out[b * SS + t]       = 0.5f * (e1a * r1 + e2a * r2);
    out[b * SS + t + 256] = 0.5f * (e1b * r1 + e2b * r2);
}

// ---------------------------------------------------------------------------
extern "C" void kernel_launch(void* const* d_in, const int* in_sizes, int n_in,
                              void* d_out, int out_size, void* d_ws, size_t ws_size,
                              hipStream_t stream) {
    const float* embeds  = (const float*)d_in[0];
    const int*   e1_idx  = (const int*)d_in[1];
    const int*   e2_idx  = (const int*)d_in[2];
    const int*   e1_mask = (const int*)d_in[3];
    const int*   e2_mask = (const int*)d_in[4];
    float* out = (float*)d_out;

    float* ws    = (float*)d_ws;
    float* pool1 = ws;                         // B*D
    float* pool2 = ws + BB * DD;               // B*D
    float* l1    = ws + 2 * BB * DD;           // B*S
    float* l2    = ws + 2 * BB * DD + BB * SS; // B*S

    pool_kernel<<<BB * 4, 64, 0, stream>>>(embeds, e1_idx, e2_idx,
                                           e1_mask, e2_mask, pool1, pool2);
    dots_kernel<<<BB * SS / 16, 256, 0, stream>>>(embeds, pool1, pool2, l1, l2);
    softmax_kernel<<<BB, 256, 0, stream>>>(l1, l2, out);
}